// Round 10
// baseline (223.129 us; speedup 1.0000x reference)
//
#include <hip/hip_runtime.h>
#include <hip/hip_bf16.h>

#define NN 20000
#define IN 128
#define HH 2
#define DD 32
#define HD 64
#define KK 3
#define RR 5
#define EE 320000
#define NEG 0.2f

#define PADK 136
#define NB 313      // buckets per relation (64 dsts each)
#define NBLK 64     // partition blocks per relation
#define CHUNK 5000  // EE / NBLK
#define CAP 2048    // slots per bucket; stride = 2^11
#define NBCAP (NB * CAP)
#define RPS 20004   // rowp row stride
#define HTOT (NN * IN / 4)   // float4 chunks of h
#define PARTB (RR * NBLK)    // 320 part blocks prefixed to cvt launch
#define CVTB ((RR * 128 * IN + NN * IN / 4 + 255) / 256)

typedef short v8s __attribute__((ext_vector_type(8)));
typedef float v4f __attribute__((ext_vector_type(4)));
typedef _Float16 hf8 __attribute__((ext_vector_type(8)));

__device__ __forceinline__ ushort f2b(float f) {
    unsigned u = __float_as_uint(f);
    unsigned r = (u + 0x7fff + ((u >> 16) & 1)) >> 16;   // RNE
    return (ushort)r;
}
__device__ __forceinline__ ushort f2h(float f) {
    _Float16 h = (_Float16)f;
    return __builtin_bit_cast(ushort, h);
}
__device__ __forceinline__ float h2f(ushort u) {
    _Float16 h = __builtin_bit_cast(_Float16, u);
    return (float)h;
}
__device__ __forceinline__ float2 up2(unsigned u) {
    return make_float2(h2f((ushort)(u & 0xFFFF)), h2f((ushort)(u >> 16)));
}

// ---------------------------------------------------------------------------
// K0: MERGED cvt + partition (attribution split: proj now gets its own row).
// Blocks [0,PARTB): edge partition (bcnt pre-zeroed via hipMemsetAsync).
// Blocks [PARTB,..): weight/feature bf16 conversion (BW-bound, overlaps
// the partition's atomic/scatter phases).
// ---------------------------------------------------------------------------
__global__ __launch_bounds__(256) void cvtpart_kernel(
    const float* __restrict__ h, const float* __restrict__ fcw,
    const float* __restrict__ resw, ushort* __restrict__ wb,
    ushort* __restrict__ hb,
    const int* __restrict__ src, const int* __restrict__ dst,
    int* __restrict__ bcnt, unsigned* __restrict__ bucketRec)
{
    __shared__ int hh[NB];
    int tid = threadIdx.x;

    if (blockIdx.x < PARTB) {
        // ---- partition path (5000-edge chunk) ----
        int r = blockIdx.x >> 6;
        int blk = blockIdx.x & 63;
        for (int i = tid; i < NB; i += 256) hh[i] = 0;
        __syncthreads();
        const int* S = src + (size_t)r * EE + blk * CHUNK;
        const int* D = dst + (size_t)r * EE + blk * CHUNK;
        for (int i = tid; i < CHUNK; i += 256)
            atomicAdd(&hh[D[i] >> 6], 1);
        __syncthreads();
        for (int i = tid; i < NB; i += 256) {
            int c = hh[i];
            hh[i] = c ? atomicAdd(&bcnt[r * NB + i], c) : 0;
        }
        __syncthreads();
        unsigned* BR = bucketRec + (size_t)r * NBCAP;
        for (int i = tid; i < CHUNK; i += 256) {
            int s = S[i], d = D[i];
            int b = d >> 6;
            int pos = atomicAdd(&hh[b], 1);
            if (pos < CAP)
                BR[((size_t)b << 11) + pos] = (unsigned)s | ((unsigned)(d & 63) << 15);
        }
        return;
    }

    // ---- conversion path ----
    int j = (blockIdx.x - PARTB) * 256 + tid;
    if (j < RR * 128 * IN) {
        int k = j & 127;
        int c = (j >> 7) & 127;
        int r = j >> 14;
        float v = (c < HD) ? fcw[(r * IN + k) * HD + c] : resw[(r * IN + k) * HD + (c - HD)];
        wb[j] = f2b(v);
    }
    int t = j - RR * 128 * IN;
    if (t >= 0 && t < HTOT) {
        float4 v = ((const float4*)h)[t];
        ((ushort4*)hb)[t] = make_ushort4(f2b(v.x), f2b(v.y), f2b(v.z), f2b(v.w));
    }
}

// ---------------------------------------------------------------------------
// K1: projection ONLY (own rocprof row for attribution). A staged in LDS
// (17.4KB); MFMA B-operand direct from global (wb L2-hot); epilogue
// transposed through As -> coalesced uint4 stores; fused attn el/er.
// ---------------------------------------------------------------------------
__global__ __launch_bounds__(256) void proj_kernel(
    const ushort* __restrict__ hb, const ushort* __restrict__ wb,
    const float* __restrict__ attn_l, const float* __restrict__ attn_r,
    ushort* __restrict__ t0, ushort* __restrict__ resh,
    float* __restrict__ el, float* __restrict__ er)
{
    __shared__ ushort As[64 * PADK];
    int tid = threadIdx.x;
    int bx = blockIdx.x;
    int r = bx / 313;
    int tile = bx - r * 313;
    int n0 = tile * 64;

    #pragma unroll
    for (int i = 0; i < 4; i++) {
        int c = tid + 256 * i;
        int row = c >> 4;            // 16 uint4 per row
        int off = (c & 15) * 8;
        int gn = n0 + row;
        uint4 v = make_uint4(0u, 0u, 0u, 0u);
        if (gn < NN) v = *(const uint4*)&hb[(size_t)gn * IN + off];
        *(uint4*)&As[row * PADK + off] = v;
    }
    __syncthreads();

    int w = tid >> 6, lane = tid & 63;
    int lm = lane & 15, lq = lane >> 4;

    v4f acc[4][2];
    #pragma unroll
    for (int mt = 0; mt < 4; mt++)
        #pragma unroll
        for (int nt = 0; nt < 2; nt++) acc[mt][nt] = (v4f){0.f, 0.f, 0.f, 0.f};

    const ushort* Ab = &As[lm * PADK + lq * 8];
    const ushort* wr = wb + (size_t)r * 128 * IN;
    const ushort* Bg = wr + (size_t)(w * 32 + lm) * IN + lq * 8;

    #pragma unroll
    for (int ks = 0; ks < 4; ks++) {
        v8s a[4], b[2];
        #pragma unroll
        for (int mt = 0; mt < 4; mt++) a[mt] = *(const v8s*)(Ab + mt * 16 * PADK + ks * 32);
        #pragma unroll
        for (int nt = 0; nt < 2; nt++) b[nt] = *(const v8s*)(Bg + nt * 16 * IN + ks * 32);
        #pragma unroll
        for (int mt = 0; mt < 4; mt++)
            #pragma unroll
            for (int nt = 0; nt < 2; nt++)
                acc[mt][nt] = __builtin_amdgcn_mfma_f32_16x16x32_bf16(a[mt], b[nt], acc[mt][nt], 0, 0, 0);
    }

    // attn epilogue (from fp32 acc, before acc is consumed by transpose)
    if (w < 2) {
        float al0 = attn_l[(r * HH + w) * DD + lm];
        float al1 = attn_l[(r * HH + w) * DD + lm + 16];
        float ar0 = attn_r[(r * HH + w) * DD + lm];
        float ar1 = attn_r[(r * HH + w) * DD + lm + 16];
        #pragma unroll
        for (int mt = 0; mt < 4; mt++) {
            #pragma unroll
            for (int p = 0; p < 4; p++) {
                float pl = acc[mt][0][p] * al0 + acc[mt][1][p] * al1;
                float pr = acc[mt][0][p] * ar0 + acc[mt][1][p] * ar1;
                #pragma unroll
                for (int off = 1; off < 16; off <<= 1) {
                    pl += __shfl_xor(pl, off, 64);
                    pr += __shfl_xor(pr, off, 64);
                }
                if (lm == 0) {
                    int node = n0 + mt * 16 + lq * 4 + p;
                    if (node < NN) {
                        el[((size_t)r * NN + node) * HH + w] = pl;
                        er[((size_t)r * NN + node) * HH + w] = pr;
                    }
                }
            }
        }
    }

    // transpose acc -> As (dead after MFMA) -> coalesced stores
    __syncthreads();
    int colbase = w * 32 + lm;
    #pragma unroll
    for (int mt = 0; mt < 4; mt++)
        #pragma unroll
        for (int nt = 0; nt < 2; nt++)
            #pragma unroll
            for (int p = 0; p < 4; p++)
                As[(mt * 16 + lq * 4 + p) * PADK + colbase + nt * 16] = f2h(acc[mt][nt][p]);
    __syncthreads();
    #pragma unroll
    for (int i = 0; i < 2; i++) {
        int c = tid + 256 * i;        // 512 chunks: 64 rows x 8 uint4
        int row = c >> 3;
        int off = (c & 7) * 8;
        int gn = n0 + row;
        if (gn < NN) {
            *(uint4*)&t0[((size_t)r * NN + gn) * HD + off]   = *(const uint4*)&As[row * PADK + off];
            *(uint4*)&resh[((size_t)r * NN + gn) * HD + off] = *(const uint4*)&As[row * PADK + 64 + off];
        }
    }
}

// ---------------------------------------------------------------------------
// B: bsort + softmax + FUSED HOP1 (R7 structure, 1-ahead pipeline).
// ---------------------------------------------------------------------------
__global__ __launch_bounds__(256) void bsort_alpha_hop1_kernel(
    const unsigned* __restrict__ bucketRec, const int* __restrict__ bcnt,
    const float* __restrict__ el, const float* __restrict__ er,
    const ushort* __restrict__ t0, uint2* __restrict__ csrE,
    int* __restrict__ rowp, ushort* __restrict__ t1)
{
    __shared__ int cnt64s[4][64];
    __shared__ int segS[65];
    __shared__ int cur[64];
    __shared__ int pbS[64];
    __shared__ float2 erL[64];
    __shared__ float2 mx2[64];
    __shared__ float2 inv2[64];
    __shared__ unsigned sSD[CAP];
    __shared__ unsigned sL[CAP];      // logits (packed half2) then weights

    int bk = blockIdx.x;            // r*NB + bkt
    int r = bk / NB;
    int bkt = bk - r * NB;
    int tid = threadIdx.x;
    int wv = tid >> 6;
    int cnt = bcnt[bk];
    if (cnt > CAP - 64) cnt = CAP - 64;   // headroom for per-dst pad slots

    if (tid < 64) {
        cnt64s[0][tid] = 0; cnt64s[1][tid] = 0;
        cnt64s[2][tid] = 0; cnt64s[3][tid] = 0;
        int gn = bkt * 64 + tid;
        erL[tid] = (gn < NN) ? ((const float2*)er)[(size_t)r * NN + gn]
                             : make_float2(0.f, 0.f);
    }
    __syncthreads();
    const unsigned* BR = bucketRec + (size_t)bk * CAP;
    for (int i = tid; i < cnt; i += 256)
        atomicAdd(&cnt64s[wv][(BR[i] >> 15) & 63], 1);
    __syncthreads();
    if (tid < 64) {
        int v = cnt64s[0][tid] + cnt64s[1][tid] + cnt64s[2][tid] + cnt64s[3][tid];
        int x = v;
        int y = v & 1;
        #pragma unroll
        for (int off = 1; off < 64; off <<= 1) {
            int tx = __shfl_up(x, off, 64);
            int ty = __shfl_up(y, off, 64);
            if (tid >= off) { x += tx; y += ty; }
        }
        segS[tid] = x - v;
        cur[tid]  = x - v;
        pbS[tid]  = (x - v) + (y - (v & 1));   // even-aligned padded begin
        if (tid == 63) segS[64] = x;
    }
    __syncthreads();
    const float2* el2 = (const float2*)el + (size_t)r * NN;
    for (int i = tid; i < cnt; i += 256) {
        unsigned rec = BR[i];
        int s = rec & 0x7FFF;
        int d = (rec >> 15) & 63;
        float2 a = el2[s];
        float2 b = erL[d];
        float l0 = a.x + b.x; l0 = l0 > 0.f ? l0 : NEG * l0;
        float l1 = a.y + b.y; l1 = l1 > 0.f ? l1 : NEG * l1;
        int pos = atomicAdd(&cur[d], 1);
        sSD[pos] = rec;
        sL[pos] = (unsigned)f2h(l0) | ((unsigned)f2h(l1) << 16);
    }
    __syncthreads();
    // wave-parallel per-dst softmax: 4 threads per dst, shfl_xor(1,2) reduce
    {
        int d = tid >> 2, sub = tid & 3;
        int b0 = segS[d], e0 = segS[d + 1];
        float m0 = -1e30f, m1 = -1e30f;
        for (int i = b0 + sub; i < e0; i += 4) {
            float2 l = up2(sL[i]);
            m0 = fmaxf(m0, l.x); m1 = fmaxf(m1, l.y);
        }
        m0 = fmaxf(m0, __shfl_xor(m0, 1, 64));
        m0 = fmaxf(m0, __shfl_xor(m0, 2, 64));
        m1 = fmaxf(m1, __shfl_xor(m1, 1, 64));
        m1 = fmaxf(m1, __shfl_xor(m1, 2, 64));
        float s0 = 0.f, s1 = 0.f;
        for (int i = b0 + sub; i < e0; i += 4) {
            float2 l = up2(sL[i]);
            s0 += __expf(l.x - m0); s1 += __expf(l.y - m1);
        }
        s0 += __shfl_xor(s0, 1, 64); s0 += __shfl_xor(s0, 2, 64);
        s1 += __shfl_xor(s1, 1, 64); s1 += __shfl_xor(s1, 2, 64);
        if (sub == 0) {
            mx2[d] = make_float2(m0, m1);
            inv2[d] = make_float2(1.f / fmaxf(s0, 1e-9f), 1.f / fmaxf(s1, 1e-9f));
            int gn = bkt * 64 + d;
            if (gn < NN) {
                int len = e0 - b0;
                rowp[r * RPS + gn] =
                    (int)(((unsigned)(bkt * CAP + pbS[d])) | ((unsigned)len << 20));
            }
        }
    }
    __syncthreads();
    uint2* E = csrE + (size_t)bk * CAP;
    for (int i = tid; i < cnt; i += 256) {
        unsigned rec = sSD[i];
        int d = (rec >> 15) & 63;
        float2 l = up2(sL[i]);
        float w0 = __expf(l.x - mx2[d].x) * inv2[d].x;
        float w1 = __expf(l.y - mx2[d].y) * inv2[d].y;
        unsigned wp = (unsigned)f2h(w0) | ((unsigned)f2h(w1) << 16);
        E[pbS[d] + (i - segS[d])] = make_uint2(rec, wp);
        sL[i] = wp;                       // repack: weights for hop1 phase
    }
    if (tid < 64) {
        int len = segS[tid + 1] - segS[tid];
        if (len & 1) E[pbS[tid] + len] = make_uint2(0u, 0u);   // pad slot
    }
    __syncthreads();

    // ---- fused hop1: 8-lane groups, recs/weights broadcast from LDS ----
    int lane = tid & 63;
    int g = lane >> 3;
    int f = (lane & 7) * 8;
    int sh = ((lane >> 2) & 1) * 16;
    const ushort* T0 = t0 + (size_t)r * NN * HD;
    #pragma unroll
    for (int half = 0; half < 2; half++) {
        int d = half * 32 + wv * 8 + g;
        int b0 = segS[d];
        int len = segS[d + 1] - b0;
        float acc[8] = {0.f, 0.f, 0.f, 0.f, 0.f, 0.f, 0.f, 0.f};
        if (len > 0) {
            float wC = h2f((ushort)(sL[b0] >> sh));
            int sC = sSD[b0] & 0x7FFF;
            hf8 fC = *(const hf8*)&T0[(size_t)sC * HD + f];
            for (int j = 0; j < len; j++) {
                int jn = j + 1 < len ? j + 1 : len - 1;
                float wN = h2f((ushort)(sL[b0 + jn] >> sh));
                int sN = sSD[b0 + jn] & 0x7FFF;
                hf8 fN = *(const hf8*)&T0[(size_t)sN * HD + f];
                #pragma unroll
                for (int k = 0; k < 8; k++) acc[k] += wC * (float)fC[k];
                wC = wN; fC = fN;
            }
        }
        int node = bkt * 64 + d;
        if (node < NN) {
            ushort o[8];
            #pragma unroll
            for (int k = 0; k < 8; k++) o[k] = f2h(acc[k]);
            *(uint4*)&t1[((size_t)r * NN + node) * HD + f] = *(uint4*)o;
        }
    }
}

// ---------------------------------------------------------------------------
// K6 (hop2): paired-record single stream, even-aligned segments,
// uint4 record loads (2 edges/VMEM), 2-ahead rec / 1-ahead feat pipeline.
// ---------------------------------------------------------------------------
__global__ __launch_bounds__(256) void hop_kernel(
    const ushort* __restrict__ tin, ushort* __restrict__ tout,
    const uint2* __restrict__ csrE, const int* __restrict__ rowp)
{
    int nbk = gridDim.x;
    int q = nbk >> 3, rmd = nbk & 7;
    int xcd = blockIdx.x & 7, pos = blockIdx.x >> 3;
    int bid = (xcd < rmd ? xcd * (q + 1) : rmd * (q + 1) + (xcd - rmd) * q) + pos;

    int w = (bid * 256 + (int)threadIdx.x) >> 6;
    if (w >= RR * (NN / 8)) return;
    int lane = threadIdx.x & 63;
    int g = lane >> 3;
    int f = (lane & 7) * 8;
    int sh = ((lane >> 2) & 1) * 16;
    int r = w / (NN / 8);
    int n0 = (w - r * (NN / 8)) * 8;

    unsigned pv = (unsigned)rowp[r * RPS + n0 + g];
    int bg = (int)(pv & 0xFFFFF);
    int len = (int)(pv >> 20);
    int pairs = (len + 1) >> 1;
    int lastP = pairs > 0 ? pairs - 1 : 0;

    const ushort* T = tin + (size_t)r * NN * HD;
    const uint4* E4 = (const uint4*)(csrE + (size_t)r * NBCAP);
    int base4 = bg >> 1;

    uint4 rC = E4[base4];
    uint4 rN = E4[base4 + (1 < pairs ? 1 : lastP)];
    int s0 = (int)(rC.x & 0x7FFF); s0 = s0 < NN ? s0 : 0;
    int s1 = (int)(rC.z & 0x7FFF); s1 = s1 < NN ? s1 : 0;
    hf8 f0 = *(const hf8*)&T[(size_t)s0 * HD + f];
    hf8 f1 = *(const hf8*)&T[(size_t)s1 * HD + f];

    float acc[8] = {0.f, 0.f, 0.f, 0.f, 0.f, 0.f, 0.f, 0.f};
    #pragma unroll 2
    for (int j = 0; j < pairs; j++) {
        int j2 = j + 2 < pairs ? j + 2 : lastP;
        uint4 r2 = E4[base4 + j2];
        int n0i = (int)(rN.x & 0x7FFF); n0i = n0i < NN ? n0i : 0;
        int n1i = (int)(rN.z & 0x7FFF); n1i = n1i < NN ? n1i : 0;
        hf8 g0 = *(const hf8*)&T[(size_t)n0i * HD + f];
        hf8 g1 = *(const hf8*)&T[(size_t)n1i * HD + f];
        float w0 = h2f((ushort)(rC.y >> sh));
        float w1 = h2f((ushort)(rC.w >> sh));
        #pragma unroll
        for (int k = 0; k < 8; k++) {
            acc[k] += w0 * (float)f0[k];
            acc[k] += w1 * (float)f1[k];
        }
        rC = rN; rN = r2;
        f0 = g0; f1 = g1;
    }
    ushort o[8];
    #pragma unroll
    for (int k = 0; k < 8; k++) o[k] = f2h(acc[k]);
    *(uint4*)&tout[((size_t)r * NN + n0 + g) * HD + f] = *(uint4*)o;
}

// ---------------------------------------------------------------------------
// K7: FUSED hop3 + final (no atomics; per-relation partial stores), R7
// pipeline depth.
// ---------------------------------------------------------------------------
__global__ __launch_bounds__(256) void hop3_final_kernel(
    const ushort* __restrict__ t0, const ushort* __restrict__ t1,
    const ushort* __restrict__ t2, const ushort* __restrict__ resh,
    const uint2* __restrict__ csrE, const int* __restrict__ rowp,
    const float* __restrict__ hal, const float* __restrict__ har,
    const float* __restrict__ w_rel, const float* __restrict__ b_rel,
    float* __restrict__ outP)
{
    int nbk = gridDim.x;
    int q = nbk >> 3, rmd = nbk & 7;
    int xcd = blockIdx.x & 7, pos = blockIdx.x >> 3;
    int bid = (xcd < rmd ? xcd * (q + 1) : rmd * (q + 1) + (xcd - rmd) * q) + pos;

    int wid = (bid * 256 + (int)threadIdx.x) >> 6;
    if (wid >= RR * (NN / 8)) return;
    int lane = threadIdx.x & 63;
    int g = lane >> 3;                 // node within wave's group of 8
    int ll = lane & 7;
    int f = ll * 8;                    // feat base = h_*32 + fq*8
    int h_ = ll >> 2;
    int fq = ll & 3;
    int sh = h_ * 16;
    int r = wid / (NN / 8);
    int n = (wid - r * (NN / 8)) * 8 + g;

    // ---- phase 1: t3 row (hop3) via paired gather from t2 ----
    unsigned pv = (unsigned)rowp[r * RPS + n];
    int bg = (int)(pv & 0xFFFFF);
    int len = (int)(pv >> 20);
    int pairs = (len + 1) >> 1;
    int lastP = pairs > 0 ? pairs - 1 : 0;

    const ushort* T = t2 + (size_t)r * NN * HD;
    const uint4* E4 = (const uint4*)(csrE + (size_t)r * NBCAP);
    int base4 = bg >> 1;

    uint4 rC = E4[base4];
    uint4 rN = E4[base4 + (1 < pairs ? 1 : lastP)];
    int s0 = (int)(rC.x & 0x7FFF); s0 = s0 < NN ? s0 : 0;
    int s1 = (int)(rC.z & 0x7FFF); s1 = s1 < NN ? s1 : 0;
    hf8 f0 = *(const hf8*)&T[(size_t)s0 * HD + f];
    hf8 f1 = *(const hf8*)&T[(size_t)s1 * HD + f];

    float t3row[8] = {0.f, 0.f, 0.f, 0.f, 0.f, 0.f, 0.f, 0.f};
    #pragma unroll 2
    for (int j = 0; j < pairs; j++) {
        int j2 = j + 2 < pairs ? j + 2 : lastP;
        uint4 r2 = E4[base4 + j2];
        int n0i = (int)(rN.x & 0x7FFF); n0i = n0i < NN ? n0i : 0;
        int n1i = (int)(rN.z & 0x7FFF); n1i = n1i < NN ? n1i : 0;
        hf8 g0 = *(const hf8*)&T[(size_t)n0i * HD + f];
        hf8 g1 = *(const hf8*)&T[(size_t)n1i * HD + f];
        float w0 = h2f((ushort)(rC.y >> sh));
        float w1 = h2f((ushort)(rC.w >> sh));
        #pragma unroll
        for (int k = 0; k < 8; k++) {
            t3row[k] += w0 * (float)f0[k];
            t3row[k] += w1 * (float)f1[k];
        }
        rC = rN; rN = r2;
        f0 = g0; f1 = g1;
    }

    // ---- phase 2: final's r-term ----
    float wr = b_rel[r];
    #pragma unroll
    for (int j = 0; j < RR; j++) wr += w_rel[r * RR + j];
    const float* hp = hal + (r * HH + h_) * DD + fq * 8;
    const float* gp = har + (r * HH + h_) * DD + fq * 8;
    float4 ha0 = *(const float4*)hp;
    float4 ha1 = *(const float4*)(hp + 4);
    float4 hr0 = *(const float4*)gp;
    float4 hr1 = *(const float4*)(gp + 4);
    float halc[8] = {ha0.x, ha0.y, ha0.z, ha0.w, ha1.x, ha1.y, ha1.z, ha1.w};
    float harc[8] = {hr0.x, hr0.y, hr0.z, hr0.w, hr1.x, hr1.y, hr1.z, hr1.w};

    size_t tbase = ((size_t)r * NN + n) * HD + f;
    const ushort* tb[3] = {t0, t1, t2};
    uint4 tv[3];
    float sq[4], dl[4], dr = 0.f;
    #pragma unroll
    for (int k = 0; k < 3; k++) {
        tv[k] = *(const uint4*)(tb[k] + tbase);
        unsigned ww[4] = {tv[k].x, tv[k].y, tv[k].z, tv[k].w};
        float s = 0.f, d1 = 0.f;
        #pragma unroll
        for (int j = 0; j < 4; j++) {
            float2 v = up2(ww[j]);
            s  += v.x * v.x + v.y * v.y;
            d1 += v.x * halc[2 * j] + v.y * halc[2 * j + 1];
            if (k == 0)
                dr += v.x * harc[2 * j] + v.y * harc[2 * j + 1];
        }
        sq[k] = s; dl[k] = d1;
    }
    {
        float s = 0.f, d1 = 0.f;
        #pragma unroll
        for (int j = 0; j < 8; j++) {
            s += t3row[j] * t3row[j];
            d1 += t3row[j] * halc[j];
        }
        sq[3] = s; dl[3] = d1;
    }
    #pragma unroll
    for (int k = 0; k < 4; k++) {
        sq[k] += __shfl_xor(sq[k], 1, 64); sq[k] += __shfl_xor(sq[k], 2, 64);
        dl[k] += __shfl_xor(dl[k], 1, 64); dl[k] += __shfl_xor(dl[k], 2, 64);
    }
    dr += __shfl_xor(dr, 1, 64); dr += __shfl_xor(dr, 2, 64);

    float inv[4], lg[4], mx = -1e30f;
    #pragma unroll
    for (int k = 0; k < 4; k++)
        inv[k] = 1.f / fmaxf(sqrtf(sq[k]), 1e-9f);
    #pragma unroll
    for (int k = 0; k < 4; k++) {
        float l = dl[k] * inv[k] + dr * inv[0];
        l = l > 0.f ? l : NEG * l;
        lg[k] = l;
        mx = fmaxf(mx, l);
    }
    float ssum = 0.f;
    #pragma unroll
    for (int k = 0; k < 4; k++) { lg[k] = __expf(lg[k] - mx); ssum += lg[k]; }
    float sw = wr / ssum;

    float o[8];
    #pragma unroll
    for (int d = 0; d < 8; d++) o[d] = 0.f;
    #pragma unroll
    for (int k = 0; k < 3; k++) {
        float coef = lg[k] * inv[k] * sw;
        unsigned ww[4] = {tv[k].x, tv[k].y, tv[k].z, tv[k].w};
        #pragma unroll
        for (int j = 0; j < 4; j++) {
            float2 v = up2(ww[j]);
            o[2 * j]     += coef * v.x;
            o[2 * j + 1] += coef * v.y;
        }
    }
    {
        float coef = lg[3] * inv[3] * sw;
        #pragma unroll
        for (int j = 0; j < 8; j++) o[j] += coef * t3row[j];
    }
    uint4 rv = *(const uint4*)(resh + tbase);
    unsigned rw[4] = {rv.x, rv.y, rv.z, rv.w};
    #pragma unroll
    for (int j = 0; j < 4; j++) {
        float2 v = up2(rw[j]);
        o[2 * j]     += wr * v.x;
        o[2 * j + 1] += wr * v.y;
    }

    // head-mean within the 8-lane node group, then PLAIN partial store
    float p[8];
    #pragma unroll
    for (int j = 0; j < 8; j++) p[j] = __shfl_down(o[j], 4, 64);
    if (h_ == 0) {
        float4* op = (float4*)(outP + ((size_t)r * NN + n) * DD + fq * 8);
        op[0] = make_float4(0.5f * (o[0] + p[0]), 0.5f * (o[1] + p[1]),
                            0.5f * (o[2] + p[2]), 0.5f * (o[3] + p[3]));
        op[1] = make_float4(0.5f * (o[4] + p[4]), 0.5f * (o[5] + p[5]),
                            0.5f * (o[6] + p[6]), 0.5f * (o[7] + p[7]));
    }
}

// ---------------------------------------------------------------------------
// K8: relation-sum reduce: out[n][d] = sum_r outP[r][n][d].
// ---------------------------------------------------------------------------
__global__ __launch_bounds__(256) void reduce_kernel(
    const float* __restrict__ outP, float* __restrict__ out)
{
    int i = blockIdx.x * 256 + threadIdx.x;   // over NN*DD/4 float4s
    if (i >= NN * DD / 4) return;
    const float4* P = (const float4*)outP;
    float4 s = P[i];
    #pragma unroll
    for (int r = 1; r < RR; r++) {
        float4 v = P[(size_t)r * (NN * DD / 4) + i];
        s.x += v.x; s.y += v.y; s.z += v.z; s.w += v.w;
    }
    ((float4*)out)[i] = s;
}

// ---------------------------------------------------------------------------
extern "C" void kernel_launch(void* const* d_in, const int* in_sizes, int n_in,
                              void* d_out, int out_size, void* d_ws, size_t ws_size,
                              hipStream_t stream) {
    (void)in_sizes; (void)n_in; (void)out_size; (void)ws_size;
    const float* h     = (const float*)d_in[0];
    const int*   src   = (const int*)d_in[1];
    const int*   dst   = (const int*)d_in[2];
    const float* fcw   = (const float*)d_in[3];
    const float* resw  = (const float*)d_in[4];
    const float* atl   = (const float*)d_in[5];
    const float* atr   = (const float*)d_in[6];
    const float* hal   = (const float*)d_in[7];
    const float* har   = (const float*)d_in[8];
    const float* wrel  = (const float*)d_in[9];
    const float* brel  = (const float*)d_in[10];
    float* out = (float*)d_out;

    float* ws = (float*)d_ws;
    size_t off = 0;
    float* el   = ws + off;  off += (size_t)RR * NN * HH;
    float* er   = ws + off;  off += (size_t)RR * NN * HH;
    uint2* csrE = (uint2*)(ws + off);      off += (size_t)RR * NBCAP * 2;
    unsigned* bucketRec = (unsigned*)(ws + off); off += (size_t)RR * NBCAP;
    ushort* resh = (ushort*)(ws + off);    off += (size_t)RR * NN * HD / 2;
    ushort* t0  = (ushort*)(ws + off);     off += (size_t)RR * NN * HD / 2;
    ushort* t1  = (ushort*)(ws + off);     off += (size_t)RR * NN * HD / 2;
    ushort* t2  = (ushort*)(ws + off);     off += (size_t)RR * NN * HD / 2;
    ushort* wb  = (ushort*)(ws + off);     off += (size_t)RR * 128 * IN / 2;
    ushort* hb  = (ushort*)(ws + off);     off += (size_t)NN * IN / 2;
    float* outP = ws + off;          off += (size_t)RR * NN * DD;
    int* rowp   = (int*)(ws + off);  off += (size_t)RR * RPS;
    int* bcnt   = (int*)(ws + off);  off += (size_t)RR * NB;

    hipMemsetAsync(bcnt, 0, (size_t)RR * NB * sizeof(int), stream);
    cvtpart_kernel<<<PARTB + CVTB, 256, 0, stream>>>(h, fcw, resw, wb, hb,
                                                     src, dst, bcnt, bucketRec);
    proj_kernel<<<313 * RR, 256, 0, stream>>>(hb, wb, atl, atr, t0, resh, el, er);
    bsort_alpha_hop1_kernel<<<RR * NB, 256, 0, stream>>>(bucketRec, bcnt, el, er, t0, csrE, rowp, t1);
    hop_kernel<<<(RR * (NN / 8) + 3) / 4, 256, 0, stream>>>(t1, t2, csrE, rowp);
    hop3_final_kernel<<<(RR * (NN / 8) + 3) / 4, 256, 0, stream>>>(t0, t1, t2, resh, csrE, rowp,
                                                                   hal, har, wrel, brel, outP);
    reduce_kernel<<<(NN * DD / 4 + 255) / 256, 256, 0, stream>>>(outP, out);
}

// Round 11
// 201.125 us; speedup vs baseline: 1.1094x; 1.1094x over previous
//
#include <hip/hip_runtime.h>
#include <hip/hip_bf16.h>

#define NN 20000
#define IN 128
#define HH 2
#define DD 32
#define HD 64
#define KK 3
#define RR 5
#define EE 320000
#define NEG 0.2f

#define PADK 136
#define NB 313      // buckets per relation (64 dsts each)
#define NBLK 64     // partition blocks per relation
#define CHUNK 5000  // EE / NBLK
#define CAP 2048    // slots per bucket; stride = 2^11
#define NBCAP (NB * CAP)
#define RPS 20004   // rowp row stride
#define HTOT (NN * IN / 4)   // float4 chunks of h
#define PARTB (RR * NBLK)    // 320 part blocks prefixed to proj launch

typedef short v8s __attribute__((ext_vector_type(8)));
typedef float v4f __attribute__((ext_vector_type(4)));
typedef _Float16 hf8 __attribute__((ext_vector_type(8)));

__device__ __forceinline__ ushort f2b(float f) {
    unsigned u = __float_as_uint(f);
    unsigned r = (u + 0x7fff + ((u >> 16) & 1)) >> 16;   // RNE
    return (ushort)r;
}
__device__ __forceinline__ ushort f2h(float f) {
    _Float16 h = (_Float16)f;
    return __builtin_bit_cast(ushort, h);
}
__device__ __forceinline__ float h2f(ushort u) {
    _Float16 h = __builtin_bit_cast(_Float16, u);
    return (float)h;
}
__device__ __forceinline__ float2 up2(unsigned u) {
    return make_float2(h2f((ushort)(u & 0xFFFF)), h2f((ushort)(u >> 16)));
}
__device__ __forceinline__ int xcd_swz(int b, int n) {
    int q = n >> 3, rmd = n & 7;
    int xcd = b & 7, pos = b >> 3;
    return (xcd < rmd ? xcd * (q + 1) : rmd * (q + 1) + (xcd - rmd) * q) + pos;
}

// ---------------------------------------------------------------------------
// K0: weights -> wb bf16 (transposed+fused), h -> hb bf16, bcnt zeroing.
// ---------------------------------------------------------------------------
__global__ __launch_bounds__(256) void cvt_kernel(
    const float* __restrict__ h, const float* __restrict__ fcw,
    const float* __restrict__ resw, ushort* __restrict__ wb,
    ushort* __restrict__ hb, int* __restrict__ bcnt)
{
    int j = blockIdx.x * 256 + threadIdx.x;
    if (j < RR * NB) bcnt[j] = 0;
    if (j < RR * 128 * IN) {
        int k = j & 127;
        int c = (j >> 7) & 127;
        int r = j >> 14;
        float v = (c < HD) ? fcw[(r * IN + k) * HD + c] : resw[(r * IN + k) * HD + (c - HD)];
        wb[j] = f2b(v);
    }
    int t = j - RR * 128 * IN;
    if (t >= 0 && t < HTOT) {
        float4 v = ((const float4*)h)[t];
        ((ushort4*)hb)[t] = make_ushort4(f2b(v.x), f2b(v.y), f2b(v.z), f2b(v.w));
    }
}

// ---------------------------------------------------------------------------
// K1: MERGED proj + partition (re-merged: R10 split showed the overlap is
// load-bearing, serialized halves cost ~15us more). proj: A in LDS (17.4KB),
// MFMA B direct from global (wb L2-hot), epilogue transposed through As ->
// coalesced uint4 stores. part: 64 chunks x 5000 edges.
// ---------------------------------------------------------------------------
__global__ __launch_bounds__(256) void projpart_kernel(
    const ushort* __restrict__ hb, const ushort* __restrict__ wb,
    const float* __restrict__ attn_l, const float* __restrict__ attn_r,
    ushort* __restrict__ t0, ushort* __restrict__ resh,
    float* __restrict__ el, float* __restrict__ er,
    const int* __restrict__ src, const int* __restrict__ dst,
    int* __restrict__ bcnt, unsigned* __restrict__ bucketRec)
{
    __shared__ ushort As[64 * PADK];
    int tid = threadIdx.x;

    if (blockIdx.x < PARTB) {
        // ---- partition path ----
        int* hh = (int*)As;   // alias: disjoint code path
        int r = blockIdx.x >> 6;
        int blk = blockIdx.x & 63;
        for (int i = tid; i < NB; i += 256) hh[i] = 0;
        __syncthreads();
        const int* S = src + (size_t)r * EE + blk * CHUNK;
        const int* D = dst + (size_t)r * EE + blk * CHUNK;
        for (int i = tid; i < CHUNK; i += 256)
            atomicAdd(&hh[D[i] >> 6], 1);
        __syncthreads();
        for (int i = tid; i < NB; i += 256) {
            int c = hh[i];
            hh[i] = c ? atomicAdd(&bcnt[r * NB + i], c) : 0;
        }
        __syncthreads();
        unsigned* BR = bucketRec + (size_t)r * NBCAP;
        for (int i = tid; i < CHUNK; i += 256) {
            int s = S[i], d = D[i];
            int b = d >> 6;
            int pos = atomicAdd(&hh[b], 1);
            if (pos < CAP)
                BR[((size_t)b << 11) + pos] = (unsigned)s | ((unsigned)(d & 63) << 15);
        }
        return;
    }

    // ---- projection path ----
    int bx = blockIdx.x - PARTB;
    int r = bx / 313;
    int tile = bx - r * 313;
    int n0 = tile * 64;

    #pragma unroll
    for (int i = 0; i < 4; i++) {
        int c = tid + 256 * i;
        int row = c >> 4;            // 16 uint4 per row
        int off = (c & 15) * 8;
        int gn = n0 + row;
        uint4 v = make_uint4(0u, 0u, 0u, 0u);
        if (gn < NN) v = *(const uint4*)&hb[(size_t)gn * IN + off];
        *(uint4*)&As[row * PADK + off] = v;
    }
    __syncthreads();

    int w = tid >> 6, lane = tid & 63;
    int lm = lane & 15, lq = lane >> 4;

    v4f acc[4][2];
    #pragma unroll
    for (int mt = 0; mt < 4; mt++)
        #pragma unroll
        for (int nt = 0; nt < 2; nt++) acc[mt][nt] = (v4f){0.f, 0.f, 0.f, 0.f};

    const ushort* Ab = &As[lm * PADK + lq * 8];
    const ushort* wr = wb + (size_t)r * 128 * IN;
    const ushort* Bg = wr + (size_t)(w * 32 + lm) * IN + lq * 8;

    #pragma unroll
    for (int ks = 0; ks < 4; ks++) {
        v8s a[4], b[2];
        #pragma unroll
        for (int mt = 0; mt < 4; mt++) a[mt] = *(const v8s*)(Ab + mt * 16 * PADK + ks * 32);
        #pragma unroll
        for (int nt = 0; nt < 2; nt++) b[nt] = *(const v8s*)(Bg + nt * 16 * IN + ks * 32);
        #pragma unroll
        for (int mt = 0; mt < 4; mt++)
            #pragma unroll
            for (int nt = 0; nt < 2; nt++)
                acc[mt][nt] = __builtin_amdgcn_mfma_f32_16x16x32_bf16(a[mt], b[nt], acc[mt][nt], 0, 0, 0);
    }

    // attn epilogue (from fp32 acc, before acc is consumed by transpose)
    if (w < 2) {
        float al0 = attn_l[(r * HH + w) * DD + lm];
        float al1 = attn_l[(r * HH + w) * DD + lm + 16];
        float ar0 = attn_r[(r * HH + w) * DD + lm];
        float ar1 = attn_r[(r * HH + w) * DD + lm + 16];
        #pragma unroll
        for (int mt = 0; mt < 4; mt++) {
            #pragma unroll
            for (int p = 0; p < 4; p++) {
                float pl = acc[mt][0][p] * al0 + acc[mt][1][p] * al1;
                float pr = acc[mt][0][p] * ar0 + acc[mt][1][p] * ar1;
                #pragma unroll
                for (int off = 1; off < 16; off <<= 1) {
                    pl += __shfl_xor(pl, off, 64);
                    pr += __shfl_xor(pr, off, 64);
                }
                if (lm == 0) {
                    int node = n0 + mt * 16 + lq * 4 + p;
                    if (node < NN) {
                        el[((size_t)r * NN + node) * HH + w] = pl;
                        er[((size_t)r * NN + node) * HH + w] = pr;
                    }
                }
            }
        }
    }

    // transpose acc -> As (dead after MFMA) -> coalesced stores
    __syncthreads();
    int colbase = w * 32 + lm;
    #pragma unroll
    for (int mt = 0; mt < 4; mt++)
        #pragma unroll
        for (int nt = 0; nt < 2; nt++)
            #pragma unroll
            for (int p = 0; p < 4; p++)
                As[(mt * 16 + lq * 4 + p) * PADK + colbase + nt * 16] = f2h(acc[mt][nt][p]);
    __syncthreads();
    #pragma unroll
    for (int i = 0; i < 2; i++) {
        int c = tid + 256 * i;        // 512 chunks: 64 rows x 8 uint4
        int row = c >> 3;
        int off = (c & 7) * 8;
        int gn = n0 + row;
        if (gn < NN) {
            *(uint4*)&t0[((size_t)r * NN + gn) * HD + off]   = *(const uint4*)&As[row * PADK + off];
            *(uint4*)&resh[((size_t)r * NN + gn) * HD + off] = *(const uint4*)&As[row * PADK + 64 + off];
        }
    }
}

// ---------------------------------------------------------------------------
// B: bsort + softmax + FUSED HOP1. NEW: bijective XCD swizzle on the block
// index (grid 1565 = 8*195+5) so each XCD's L2 serves ~1 relation's t0
// table (2.56MB fits 4MB) during the fused-hop1 gather, instead of all 5.
// ---------------------------------------------------------------------------
__global__ __launch_bounds__(256) void bsort_alpha_hop1_kernel(
    const unsigned* __restrict__ bucketRec, const int* __restrict__ bcnt,
    const float* __restrict__ el, const float* __restrict__ er,
    const ushort* __restrict__ t0, uint2* __restrict__ csrE,
    int* __restrict__ rowp, ushort* __restrict__ t1)
{
    __shared__ int cnt64s[4][64];
    __shared__ int segS[65];
    __shared__ int cur[64];
    __shared__ int pbS[64];
    __shared__ float2 erL[64];
    __shared__ float2 mx2[64];
    __shared__ float2 inv2[64];
    __shared__ unsigned sSD[CAP];
    __shared__ unsigned sL[CAP];      // logits (packed half2) then weights

    int bk = xcd_swz(blockIdx.x, gridDim.x);   // r*NB + bkt (XCD-contiguous)
    int r = bk / NB;
    int bkt = bk - r * NB;
    int tid = threadIdx.x;
    int wv = tid >> 6;
    int cnt = bcnt[bk];
    if (cnt > CAP - 64) cnt = CAP - 64;   // headroom for per-dst pad slots

    if (tid < 64) {
        cnt64s[0][tid] = 0; cnt64s[1][tid] = 0;
        cnt64s[2][tid] = 0; cnt64s[3][tid] = 0;
        int gn = bkt * 64 + tid;
        erL[tid] = (gn < NN) ? ((const float2*)er)[(size_t)r * NN + gn]
                             : make_float2(0.f, 0.f);
    }
    __syncthreads();
    const unsigned* BR = bucketRec + (size_t)bk * CAP;
    for (int i = tid; i < cnt; i += 256)
        atomicAdd(&cnt64s[wv][(BR[i] >> 15) & 63], 1);
    __syncthreads();
    if (tid < 64) {
        int v = cnt64s[0][tid] + cnt64s[1][tid] + cnt64s[2][tid] + cnt64s[3][tid];
        int x = v;
        int y = v & 1;
        #pragma unroll
        for (int off = 1; off < 64; off <<= 1) {
            int tx = __shfl_up(x, off, 64);
            int ty = __shfl_up(y, off, 64);
            if (tid >= off) { x += tx; y += ty; }
        }
        segS[tid] = x - v;
        cur[tid]  = x - v;
        pbS[tid]  = (x - v) + (y - (v & 1));   // even-aligned padded begin
        if (tid == 63) segS[64] = x;
    }
    __syncthreads();
    const float2* el2 = (const float2*)el + (size_t)r * NN;
    for (int i = tid; i < cnt; i += 256) {
        unsigned rec = BR[i];
        int s = rec & 0x7FFF;
        int d = (rec >> 15) & 63;
        float2 a = el2[s];
        float2 b = erL[d];
        float l0 = a.x + b.x; l0 = l0 > 0.f ? l0 : NEG * l0;
        float l1 = a.y + b.y; l1 = l1 > 0.f ? l1 : NEG * l1;
        int pos = atomicAdd(&cur[d], 1);
        sSD[pos] = rec;
        sL[pos] = (unsigned)f2h(l0) | ((unsigned)f2h(l1) << 16);
    }
    __syncthreads();
    // wave-parallel per-dst softmax: 4 threads per dst, shfl_xor(1,2) reduce
    {
        int d = tid >> 2, sub = tid & 3;
        int b0 = segS[d], e0 = segS[d + 1];
        float m0 = -1e30f, m1 = -1e30f;
        for (int i = b0 + sub; i < e0; i += 4) {
            float2 l = up2(sL[i]);
            m0 = fmaxf(m0, l.x); m1 = fmaxf(m1, l.y);
        }
        m0 = fmaxf(m0, __shfl_xor(m0, 1, 64));
        m0 = fmaxf(m0, __shfl_xor(m0, 2, 64));
        m1 = fmaxf(m1, __shfl_xor(m1, 1, 64));
        m1 = fmaxf(m1, __shfl_xor(m1, 2, 64));
        float s0 = 0.f, s1 = 0.f;
        for (int i = b0 + sub; i < e0; i += 4) {
            float2 l = up2(sL[i]);
            s0 += __expf(l.x - m0); s1 += __expf(l.y - m1);
        }
        s0 += __shfl_xor(s0, 1, 64); s0 += __shfl_xor(s0, 2, 64);
        s1 += __shfl_xor(s1, 1, 64); s1 += __shfl_xor(s1, 2, 64);
        if (sub == 0) {
            mx2[d] = make_float2(m0, m1);
            inv2[d] = make_float2(1.f / fmaxf(s0, 1e-9f), 1.f / fmaxf(s1, 1e-9f));
            int gn = bkt * 64 + d;
            if (gn < NN) {
                int len = e0 - b0;
                rowp[r * RPS + gn] =
                    (int)(((unsigned)(bkt * CAP + pbS[d])) | ((unsigned)len << 20));
            }
        }
    }
    __syncthreads();
    uint2* E = csrE + (size_t)bk * CAP;
    for (int i = tid; i < cnt; i += 256) {
        unsigned rec = sSD[i];
        int d = (rec >> 15) & 63;
        float2 l = up2(sL[i]);
        float w0 = __expf(l.x - mx2[d].x) * inv2[d].x;
        float w1 = __expf(l.y - mx2[d].y) * inv2[d].y;
        unsigned wp = (unsigned)f2h(w0) | ((unsigned)f2h(w1) << 16);
        E[pbS[d] + (i - segS[d])] = make_uint2(rec, wp);
        sL[i] = wp;                       // repack: weights for hop1 phase
    }
    if (tid < 64) {
        int len = segS[tid + 1] - segS[tid];
        if (len & 1) E[pbS[tid] + len] = make_uint2(0u, 0u);   // pad slot
    }
    __syncthreads();

    // ---- fused hop1: 8-lane groups, recs/weights broadcast from LDS ----
    int lane = tid & 63;
    int g = lane >> 3;
    int f = (lane & 7) * 8;
    int sh = ((lane >> 2) & 1) * 16;
    const ushort* T0 = t0 + (size_t)r * NN * HD;
    #pragma unroll
    for (int half = 0; half < 2; half++) {
        int d = half * 32 + wv * 8 + g;
        int b0 = segS[d];
        int len = segS[d + 1] - b0;
        float acc[8] = {0.f, 0.f, 0.f, 0.f, 0.f, 0.f, 0.f, 0.f};
        if (len > 0) {
            float wC = h2f((ushort)(sL[b0] >> sh));
            int sC = sSD[b0] & 0x7FFF;
            hf8 fC = *(const hf8*)&T0[(size_t)sC * HD + f];
            for (int j = 0; j < len; j++) {
                int jn = j + 1 < len ? j + 1 : len - 1;
                float wN = h2f((ushort)(sL[b0 + jn] >> sh));
                int sN = sSD[b0 + jn] & 0x7FFF;
                hf8 fN = *(const hf8*)&T0[(size_t)sN * HD + f];
                #pragma unroll
                for (int k = 0; k < 8; k++) acc[k] += wC * (float)fC[k];
                wC = wN; fC = fN;
            }
        }
        int node = bkt * 64 + d;
        if (node < NN) {
            ushort o[8];
            #pragma unroll
            for (int k = 0; k < 8; k++) o[k] = f2h(acc[k]);
            *(uint4*)&t1[((size_t)r * NN + node) * HD + f] = *(uint4*)o;
        }
    }
}

// ---------------------------------------------------------------------------
// K6 (hop2): paired-record single stream, even-aligned segments,
// uint4 record loads (2 edges/VMEM), 2-ahead rec / 1-ahead feat pipeline.
// ---------------------------------------------------------------------------
__global__ __launch_bounds__(256) void hop_kernel(
    const ushort* __restrict__ tin, ushort* __restrict__ tout,
    const uint2* __restrict__ csrE, const int* __restrict__ rowp)
{
    int bid = xcd_swz(blockIdx.x, gridDim.x);

    int w = (bid * 256 + (int)threadIdx.x) >> 6;
    if (w >= RR * (NN / 8)) return;
    int lane = threadIdx.x & 63;
    int g = lane >> 3;
    int f = (lane & 7) * 8;
    int sh = ((lane >> 2) & 1) * 16;
    int r = w / (NN / 8);
    int n0 = (w - r * (NN / 8)) * 8;

    unsigned pv = (unsigned)rowp[r * RPS + n0 + g];
    int bg = (int)(pv & 0xFFFFF);
    int len = (int)(pv >> 20);
    int pairs = (len + 1) >> 1;
    int lastP = pairs > 0 ? pairs - 1 : 0;

    const ushort* T = tin + (size_t)r * NN * HD;
    const uint4* E4 = (const uint4*)(csrE + (size_t)r * NBCAP);
    int base4 = bg >> 1;

    uint4 rC = E4[base4];
    uint4 rN = E4[base4 + (1 < pairs ? 1 : lastP)];
    int s0 = (int)(rC.x & 0x7FFF); s0 = s0 < NN ? s0 : 0;
    int s1 = (int)(rC.z & 0x7FFF); s1 = s1 < NN ? s1 : 0;
    hf8 f0 = *(const hf8*)&T[(size_t)s0 * HD + f];
    hf8 f1 = *(const hf8*)&T[(size_t)s1 * HD + f];

    float acc[8] = {0.f, 0.f, 0.f, 0.f, 0.f, 0.f, 0.f, 0.f};
    #pragma unroll 2
    for (int j = 0; j < pairs; j++) {
        int j2 = j + 2 < pairs ? j + 2 : lastP;
        uint4 r2 = E4[base4 + j2];
        int n0i = (int)(rN.x & 0x7FFF); n0i = n0i < NN ? n0i : 0;
        int n1i = (int)(rN.z & 0x7FFF); n1i = n1i < NN ? n1i : 0;
        hf8 g0 = *(const hf8*)&T[(size_t)n0i * HD + f];
        hf8 g1 = *(const hf8*)&T[(size_t)n1i * HD + f];
        float w0 = h2f((ushort)(rC.y >> sh));
        float w1 = h2f((ushort)(rC.w >> sh));
        #pragma unroll
        for (int k = 0; k < 8; k++) {
            acc[k] += w0 * (float)f0[k];
            acc[k] += w1 * (float)f1[k];
        }
        rC = rN; rN = r2;
        f0 = g0; f1 = g1;
    }
    ushort o[8];
    #pragma unroll
    for (int k = 0; k < 8; k++) o[k] = f2h(acc[k]);
    *(uint4*)&tout[((size_t)r * NN + n0 + g) * HD + f] = *(uint4*)o;
}

// ---------------------------------------------------------------------------
// K7: FUSED hop3 + final (no atomics; per-relation partial stores).
// ---------------------------------------------------------------------------
__global__ __launch_bounds__(256) void hop3_final_kernel(
    const ushort* __restrict__ t0, const ushort* __restrict__ t1,
    const ushort* __restrict__ t2, const ushort* __restrict__ resh,
    const uint2* __restrict__ csrE, const int* __restrict__ rowp,
    const float* __restrict__ hal, const float* __restrict__ har,
    const float* __restrict__ w_rel, const float* __restrict__ b_rel,
    float* __restrict__ outP)
{
    int bid = xcd_swz(blockIdx.x, gridDim.x);

    int wid = (bid * 256 + (int)threadIdx.x) >> 6;
    if (wid >= RR * (NN / 8)) return;
    int lane = threadIdx.x & 63;
    int g = lane >> 3;                 // node within wave's group of 8
    int ll = lane & 7;
    int f = ll * 8;                    // feat base = h_*32 + fq*8
    int h_ = ll >> 2;
    int fq = ll & 3;
    int sh = h_ * 16;
    int r = wid / (NN / 8);
    int n = (wid - r * (NN / 8)) * 8 + g;

    // ---- phase 1: t3 row (hop3) via paired gather from t2 ----
    unsigned pv = (unsigned)rowp[r * RPS + n];
    int bg = (int)(pv & 0xFFFFF);
    int len = (int)(pv >> 20);
    int pairs = (len + 1) >> 1;
    int lastP = pairs > 0 ? pairs - 1 : 0;

    const ushort* T = t2 + (size_t)r * NN * HD;
    const uint4* E4 = (const uint4*)(csrE + (size_t)r * NBCAP);
    int base4 = bg >> 1;

    uint4 rC = E4[base4];
    uint4 rN = E4[base4 + (1 < pairs ? 1 : lastP)];
    int s0 = (int)(rC.x & 0x7FFF); s0 = s0 < NN ? s0 : 0;
    int s1 = (int)(rC.z & 0x7FFF); s1 = s1 < NN ? s1 : 0;
    hf8 f0 = *(const hf8*)&T[(size_t)s0 * HD + f];
    hf8 f1 = *(const hf8*)&T[(size_t)s1 * HD + f];

    float t3row[8] = {0.f, 0.f, 0.f, 0.f, 0.f, 0.f, 0.f, 0.f};
    #pragma unroll 2
    for (int j = 0; j < pairs; j++) {
        int j2 = j + 2 < pairs ? j + 2 : lastP;
        uint4 r2 = E4[base4 + j2];
        int n0i = (int)(rN.x & 0x7FFF); n0i = n0i < NN ? n0i : 0;
        int n1i = (int)(rN.z & 0x7FFF); n1i = n1i < NN ? n1i : 0;
        hf8 g0 = *(const hf8*)&T[(size_t)n0i * HD + f];
        hf8 g1 = *(const hf8*)&T[(size_t)n1i * HD + f];
        float w0 = h2f((ushort)(rC.y >> sh));
        float w1 = h2f((ushort)(rC.w >> sh));
        #pragma unroll
        for (int k = 0; k < 8; k++) {
            t3row[k] += w0 * (float)f0[k];
            t3row[k] += w1 * (float)f1[k];
        }
        rC = rN; rN = r2;
        f0 = g0; f1 = g1;
    }

    // ---- phase 2: final's r-term ----
    float wr = b_rel[r];
    #pragma unroll
    for (int j = 0; j < RR; j++) wr += w_rel[r * RR + j];
    const float* hp = hal + (r * HH + h_) * DD + fq * 8;
    const float* gp = har + (r * HH + h_) * DD + fq * 8;
    float4 ha0 = *(const float4*)hp;
    float4 ha1 = *(const float4*)(hp + 4);
    float4 hr0 = *(const float4*)gp;
    float4 hr1 = *(const float4*)(gp + 4);
    float halc[8] = {ha0.x, ha0.y, ha0.z, ha0.w, ha1.x, ha1.y, ha1.z, ha1.w};
    float harc[8] = {hr0.x, hr0.y, hr0.z, hr0.w, hr1.x, hr1.y, hr1.z, hr1.w};

    size_t tbase = ((size_t)r * NN + n) * HD + f;
    const ushort* tb[3] = {t0, t1, t2};
    uint4 tv[3];
    float sq[4], dl[4], dr = 0.f;
    #pragma unroll
    for (int k = 0; k < 3; k++) {
        tv[k] = *(const uint4*)(tb[k] + tbase);
        unsigned ww[4] = {tv[k].x, tv[k].y, tv[k].z, tv[k].w};
        float s = 0.f, d1 = 0.f;
        #pragma unroll
        for (int j = 0; j < 4; j++) {
            float2 v = up2(ww[j]);
            s  += v.x * v.x + v.y * v.y;
            d1 += v.x * halc[2 * j] + v.y * halc[2 * j + 1];
            if (k == 0)
                dr += v.x * harc[2 * j] + v.y * harc[2 * j + 1];
        }
        sq[k] = s; dl[k] = d1;
    }
    {
        float s = 0.f, d1 = 0.f;
        #pragma unroll
        for (int j = 0; j < 8; j++) {
            s += t3row[j] * t3row[j];
            d1 += t3row[j] * halc[j];
        }
        sq[3] = s; dl[3] = d1;
    }
    #pragma unroll
    for (int k = 0; k < 4; k++) {
        sq[k] += __shfl_xor(sq[k], 1, 64); sq[k] += __shfl_xor(sq[k], 2, 64);
        dl[k] += __shfl_xor(dl[k], 1, 64); dl[k] += __shfl_xor(dl[k], 2, 64);
    }
    dr += __shfl_xor(dr, 1, 64); dr += __shfl_xor(dr, 2, 64);

    float inv[4], lg[4], mx = -1e30f;
    #pragma unroll
    for (int k = 0; k < 4; k++)
        inv[k] = 1.f / fmaxf(sqrtf(sq[k]), 1e-9f);
    #pragma unroll
    for (int k = 0; k < 4; k++) {
        float l = dl[k] * inv[k] + dr * inv[0];
        l = l > 0.f ? l : NEG * l;
        lg[k] = l;
        mx = fmaxf(mx, l);
    }
    float ssum = 0.f;
    #pragma unroll
    for (int k = 0; k < 4; k++) { lg[k] = __expf(lg[k] - mx); ssum += lg[k]; }
    float sw = wr / ssum;

    float o[8];
    #pragma unroll
    for (int d = 0; d < 8; d++) o[d] = 0.f;
    #pragma unroll
    for (int k = 0; k < 3; k++) {
        float coef = lg[k] * inv[k] * sw;
        unsigned ww[4] = {tv[k].x, tv[k].y, tv[k].z, tv[k].w};
        #pragma unroll
        for (int j = 0; j < 4; j++) {
            float2 v = up2(ww[j]);
            o[2 * j]     += coef * v.x;
            o[2 * j + 1] += coef * v.y;
        }
    }
    {
        float coef = lg[3] * inv[3] * sw;
        #pragma unroll
        for (int j = 0; j < 8; j++) o[j] += coef * t3row[j];
    }
    uint4 rv = *(const uint4*)(resh + tbase);
    unsigned rw[4] = {rv.x, rv.y, rv.z, rv.w};
    #pragma unroll
    for (int j = 0; j < 4; j++) {
        float2 v = up2(rw[j]);
        o[2 * j]     += wr * v.x;
        o[2 * j + 1] += wr * v.y;
    }

    // head-mean within the 8-lane node group, then PLAIN partial store
    float p[8];
    #pragma unroll
    for (int j = 0; j < 8; j++) p[j] = __shfl_down(o[j], 4, 64);
    if (h_ == 0) {
        float4* op = (float4*)(outP + ((size_t)r * NN + n) * DD + fq * 8);
        op[0] = make_float4(0.5f * (o[0] + p[0]), 0.5f * (o[1] + p[1]),
                            0.5f * (o[2] + p[2]), 0.5f * (o[3] + p[3]));
        op[1] = make_float4(0.5f * (o[4] + p[4]), 0.5f * (o[5] + p[5]),
                            0.5f * (o[6] + p[6]), 0.5f * (o[7] + p[7]));
    }
}

// ---------------------------------------------------------------------------
// K8: relation-sum reduce: out[n][d] = sum_r outP[r][n][d].
// ---------------------------------------------------------------------------
__global__ __launch_bounds__(256) void reduce_kernel(
    const float* __restrict__ outP, float* __restrict__ out)
{
    int i = blockIdx.x * 256 + threadIdx.x;   // over NN*DD/4 float4s
    if (i >= NN * DD / 4) return;
    const float4* P = (const float4*)outP;
    float4 s = P[i];
    #pragma unroll
    for (int r = 1; r < RR; r++) {
        float4 v = P[(size_t)r * (NN * DD / 4) + i];
        s.x += v.x; s.y += v.y; s.z += v.z; s.w += v.w;
    }
    ((float4*)out)[i] = s;
}

// ---------------------------------------------------------------------------
extern "C" void kernel_launch(void* const* d_in, const int* in_sizes, int n_in,
                              void* d_out, int out_size, void* d_ws, size_t ws_size,
                              hipStream_t stream) {
    (void)in_sizes; (void)n_in; (void)out_size; (void)ws_size;
    const float* h     = (const float*)d_in[0];
    const int*   src   = (const int*)d_in[1];
    const int*   dst   = (const int*)d_in[2];
    const float* fcw   = (const float*)d_in[3];
    const float* resw  = (const float*)d_in[4];
    const float* atl   = (const float*)d_in[5];
    const float* atr   = (const float*)d_in[6];
    const float* hal   = (const float*)d_in[7];
    const float* har   = (const float*)d_in[8];
    const float* wrel  = (const float*)d_in[9];
    const float* brel  = (const float*)d_in[10];
    float* out = (float*)d_out;

    float* ws = (float*)d_ws;
    size_t off = 0;
    float* el   = ws + off;  off += (size_t)RR * NN * HH;
    float* er   = ws + off;  off += (size_t)RR * NN * HH;
    uint2* csrE = (uint2*)(ws + off);      off += (size_t)RR * NBCAP * 2;
    unsigned* bucketRec = (unsigned*)(ws + off); off += (size_t)RR * NBCAP;
    ushort* resh = (ushort*)(ws + off);    off += (size_t)RR * NN * HD / 2;
    ushort* t0  = (ushort*)(ws + off);     off += (size_t)RR * NN * HD / 2;
    ushort* t1  = (ushort*)(ws + off);     off += (size_t)RR * NN * HD / 2;
    ushort* t2  = (ushort*)(ws + off);     off += (size_t)RR * NN * HD / 2;
    ushort* wb  = (ushort*)(ws + off);     off += (size_t)RR * 128 * IN / 2;
    ushort* hb  = (ushort*)(ws + off);     off += (size_t)NN * IN / 2;
    float* outP = ws + off;          off += (size_t)RR * NN * DD;
    int* rowp   = (int*)(ws + off);  off += (size_t)RR * RPS;
    int* bcnt   = (int*)(ws + off);  off += (size_t)RR * NB;

    cvt_kernel<<<(RR * 128 * IN + HTOT + 255) / 256, 256, 0, stream>>>(h, fcw, resw, wb, hb, bcnt);
    projpart_kernel<<<PARTB + 313 * RR, 256, 0, stream>>>(hb, wb, atl, atr, t0, resh, el, er,
                                                          src, dst, bcnt, bucketRec);
    bsort_alpha_hop1_kernel<<<RR * NB, 256, 0, stream>>>(bucketRec, bcnt, el, er, t0, csrE, rowp, t1);
    hop_kernel<<<(RR * (NN / 8) + 3) / 4, 256, 0, stream>>>(t1, t2, csrE, rowp);
    hop3_final_kernel<<<(RR * (NN / 8) + 3) / 4, 256, 0, stream>>>(t0, t1, t2, resh, csrE, rowp,
                                                                   hal, har, wrel, brel, outP);
    reduce_kernel<<<(NN * DD / 4 + 255) / 256, 256, 0, stream>>>(outP, out);
}